// Round 5
// baseline (190.570 us; speedup 1.0000x reference)
//
#include <hip/hip_runtime.h>

// LaplaceCostNet — MI355X (gfx950), round 5.
// R4: 144.7 µs total = mlp 64.9 + ~10 µs small kernels + ~70 µs fixed overhead.
// R5: mlp is the target.
//  (1) MFMA A-operand (weights) read straight from L2 (WT 128 KB, resident)
//      -> wbuf deleted, LDS 64->32 KB, occupancy 2->4 blocks/CU, fewer barriers.
//  (2) __sincosf -> native __sinf/__cosf (v_sin/v_cos), ~3x less encoding VALU.
//  (3) prep: coalesced + LDS transpose; fused_solve: 1024 blocks, no int div.
//
// Workspace (bytes):
//   [4096   .. 135168)   WT bf16, linear: WT[l][n][k] = Wh[l][k][n]
//   [262144 .. +1MB)     C    fp32
//   [262144+3MB .. +4MB) Vfin fp32

typedef unsigned short ushort_t;
typedef short short8 __attribute__((ext_vector_type(8)));
typedef float floatx4 __attribute__((ext_vector_type(4)));

#define HH 512
#define WW 512
#define NPIX (HH*WW)

// act swizzle: element address in a 128-elem row, 16B-chunk XOR'd with row&15
#define SW(p, f) (((p) << 7) + (((((f) >> 3) ^ ((p) & 15))) << 3) + ((f) & 7))

__device__ inline ushort_t f2bf(float f) {
    union { float f; unsigned int i; } v; v.f = f;
    unsigned int u = v.i;
    unsigned int r = u + 0x7FFFu + ((u >> 16) & 1u);  // RNE
    return (ushort_t)(r >> 16);
}
__device__ inline float bf2f(ushort_t u) {
    union { unsigned int i; float f; } v; v.i = ((unsigned int)u) << 16; return v.f;
}

// ---------------- prep: transpose+downcast weights (coalesced via LDS) ----------------
// 32 blocks: b -> l = b>>3, ng = (b>>2)&1 (64-row n-half), kq = b&3 (32-col k-quarter).
__global__ __launch_bounds__(256) void prep_kernel(const float* __restrict__ Wh,
                                                   ushort_t* __restrict__ WT) {
    __shared__ float trans[64 * 33];
    const int tid = threadIdx.x;
    const int l = blockIdx.x >> 3, ng = (blockIdx.x >> 2) & 1, kq = blockIdx.x & 3;
    const int n0 = ng * 64, k0 = kq * 32;
    const int ln = tid & 63, wv = tid >> 6;
    // read: per pass 4 k-rows (one per wave), 64 consecutive n -> fully coalesced
    #pragma unroll
    for (int pass = 0; pass < 8; ++pass) {
        int k = k0 + pass * 4 + wv;
        trans[ln * 33 + (k - k0)] = Wh[l * 16384 + k * 128 + n0 + ln];
    }
    __syncthreads();
    // write: thread t -> row n = t>>2, 8-elem chunk q = t&3 ; coalesced 16B stores
    {
        int n = tid >> 2, q = tid & 3;
        unsigned int w[4];
        #pragma unroll
        for (int j = 0; j < 4; ++j) {
            ushort_t a = f2bf(trans[n * 33 + q * 8 + 2 * j]);
            ushort_t b = f2bf(trans[n * 33 + q * 8 + 2 * j + 1]);
            w[j] = (unsigned int)a | ((unsigned int)b << 16);
        }
        *(uint4*)&WT[(l * 128 + n0 + n) * 128 + k0 + q * 8] = uint4{w[0], w[1], w[2], w[3]};
    }
}

// ---------------- MLP: enc + 4x (128x128 MFMA GEMM, relu) + output dot ----------------
// Weights = A operand, loaded per-fragment from global (L2). Act = B operand in LDS.
__global__ __launch_bounds__(256, 4) void mlp_kernel(const float* __restrict__ x,
                                                     const ushort_t* __restrict__ WT,
                                                     const float* __restrict__ benc,
                                                     const float* __restrict__ wout,
                                                     float* __restrict__ C_ws,
                                                     float* __restrict__ outbuf) {
    __shared__ __align__(16) ushort_t act[128 * 128];   // 32 KB, swizzled rows
    const int tid = threadIdx.x;
    const int p0 = blockIdx.x * 128;
    const int lane = tid & 63, wave = tid >> 6;

    // --- Fourier encoding: thread (p, h) covers f in [h*32, h*32+32), both sin & cos ---
    {
        int p = tid >> 1, h = tid & 1;
        float2 xv = ((const float2*)x)[p0 + p];
        float xq0 = 0.5f + 0.5f * xv.x, xq1 = 0.5f + 0.5f * xv.y;
        const float4* b4 = (const float4*)benc;
        #pragma unroll 4
        for (int f2 = 0; f2 < 32; f2 += 2) {
            int f = h * 32 + f2;
            float4 b = b4[f >> 1];   // benc[2f .. 2f+3]
            float vp0 = 6.28318530718f * (xq0 * b.x + xq1 * b.y);
            float vp1 = 6.28318530718f * (xq0 * b.z + xq1 * b.w);
            float s0 = __sinf(vp0), c0 = __cosf(vp0);
            float s1 = __sinf(vp1), c1 = __cosf(vp1);
            unsigned int pc = (unsigned int)f2bf(c0) | ((unsigned int)f2bf(c1) << 16);
            unsigned int ps = (unsigned int)f2bf(s0) | ((unsigned int)f2bf(s1) << 16);
            *(unsigned int*)&act[SW(p, f)]      = pc;   // cos -> n = f
            *(unsigned int*)&act[SW(p, f + 64)] = ps;   // sin -> n = f+64
        }
    }

    const int quad = lane >> 4, l16 = lane & 15;
    const int ntb = (wave >> 1) * 64;   // out-neuron range
    const int ptb = (wave & 1) * 64;    // point range

    #pragma unroll 1
    for (int l = 0; l < 4; ++l) {
        __syncthreads();   // act ready (enc or previous writeback)

        floatx4 acc[4][4];
        #pragma unroll
        for (int i = 0; i < 4; ++i)
            #pragma unroll
            for (int j = 0; j < 4; ++j)
                acc[i][j] = floatx4{0.0f, 0.0f, 0.0f, 0.0f};

        #pragma unroll
        for (int ks = 0; ks < 4; ++ks) {
            int cs = ks * 4 + quad;           // this quad's 8-elem k-chunk
            short8 af[4], bv[4];
            #pragma unroll
            for (int i = 0; i < 4; ++i) {
                int r = ntb + i * 16 + l16;   // neuron row
                af[i] = *(const short8*)&WT[((l * 128 + r) << 7) + (cs << 3)];  // global/L2
            }
            #pragma unroll
            for (int j = 0; j < 4; ++j) {
                int p = ptb + j * 16 + l16;   // point row
                bv[j] = *(const short8*)&act[(p << 7) + ((cs ^ l16) << 3)];
            }
            #pragma unroll
            for (int i = 0; i < 4; ++i)
                #pragma unroll
                for (int j = 0; j < 4; ++j)
                    acc[i][j] = __builtin_amdgcn_mfma_f32_16x16x32_bf16(af[i], bv[j], acc[i][j], 0, 0, 0);
        }
        __syncthreads();   // all act reads done before overwrite

        // writeback relu(acc) into act (swizzled): lane -> point p, neurons n0..n0+3
        #pragma unroll
        for (int i = 0; i < 4; ++i) {
            #pragma unroll
            for (int j = 0; j < 4; ++j) {
                int p = ptb + j * 16 + l16;
                int n0 = ntb + i * 16 + quad * 4;
                float r0 = fmaxf(acc[i][j][0], 0.0f);
                float r1 = fmaxf(acc[i][j][1], 0.0f);
                float r2 = fmaxf(acc[i][j][2], 0.0f);
                float r3 = fmaxf(acc[i][j][3], 0.0f);
                uint2 pk;
                pk.x = (unsigned int)f2bf(r0) | ((unsigned int)f2bf(r1) << 16);
                pk.y = (unsigned int)f2bf(r2) | ((unsigned int)f2bf(r3) << 16);
                *(uint2*)&act[SW(p, n0)] = pk;
            }
        }
    }
    __syncthreads();

    // final linear: two threads per point, 64 MACs each + shuffle combine
    {
        int p = tid >> 1, h = tid & 1;
        const float4* wo4 = (const float4*)wout;
        float sum = 0.0f;
        #pragma unroll
        for (int g = 0; g < 8; ++g) {
            int ch = h * 8 + g;
            short8 v = *(const short8*)&act[(p << 7) + ((ch ^ (p & 15)) << 3)];
            float4 wa = wo4[ch * 2], wb = wo4[ch * 2 + 1];
            sum += bf2f((ushort_t)v[0]) * wa.x + bf2f((ushort_t)v[1]) * wa.y
                 + bf2f((ushort_t)v[2]) * wa.z + bf2f((ushort_t)v[3]) * wa.w
                 + bf2f((ushort_t)v[4]) * wb.x + bf2f((ushort_t)v[5]) * wb.y
                 + bf2f((ushort_t)v[6]) * wb.z + bf2f((ushort_t)v[7]) * wb.w;
        }
        float other = __shfl_xor(sum, 1);
        if (h == 0) {
            float tot = sum + other;
            C_ws[p0 + p] = tot;
            outbuf[NPIX + p0 + p] = tot;   // output 1: C
        }
    }
}

// ---------------- fused: cost (box5 + Cs + V0) + 5 Jacobi passes ----------------
// 16x16 output tiles (1024 blocks), halo 7 -> 30x30 region, LDS stride 32 (no int div).
// Contamination-front argument: pass-t garbage ring reaches at most li<=t+1 < 7 = core.
__global__ __launch_bounds__(256) void fused_solve_kernel(const int* __restrict__ bt,
                                                          const float* __restrict__ bc,
                                                          const float* __restrict__ C_ws,
                                                          float* __restrict__ Vfin) {
    __shared__ float Va[30 * 32];
    __shared__ float Vb[30 * 32];
    __shared__ float Wp[30 * 32];   // free -> Cs (>=0), pinned/out -> -(bc+1)
    const int tid = threadIdx.x;
    const int gx0 = (blockIdx.x & 31) * 16 - 7, gy0 = (blockIdx.x >> 5) * 16 - 7;

    // Phase A: obj over [0,30)x[0,30) (0 outside grid / non-obstacle); full rows stored
    for (int c = tid; c < 30 * 32; c += 256) {
        int li = c >> 5, lj = c & 31;
        int gi = gy0 + li, gj = gx0 + lj;
        float v = 0.0f;
        if (lj < 30 && gi >= 0 && gi < HH && gj >= 0 && gj < WW) {
            int g = gi * WW + gj;
            float b = bc[g];
            if (bt[g] == 1 && b > 0.0f) v = b;
        }
        Va[c] = v;
    }
    __syncthreads();

    // Phase B: Wp and V0 over full array; active region [2,28)x[2,28)
    for (int c = tid; c < 30 * 32; c += 256) {
        int li = c >> 5, lj = c & 31;
        int gi = gy0 + li, gj = gx0 + lj;
        float w = -1.0f, v0 = 0.0f;
        if (li >= 2 && li < 28 && lj >= 2 && lj < 28 &&
            gi >= 0 && gi < HH && gj >= 0 && gj < WW) {
            int g = gi * WW + gj;
            if (bt[g] == 0) {
                float s = 0.0f;
                #pragma unroll
                for (int di = 0; di < 5; ++di)
                    #pragma unroll
                    for (int dj = 0; dj < 5; ++dj)
                        s += Va[(li + di - 2) * 32 + lj + dj - 2];
                w = fmaxf(C_ws[g], 0.0f) + s * 0.04f;
                v0 = 100.0f;
            } else {
                float b = bc[g];
                w = -b - 1.0f;
                v0 = b;
            }
        }
        Wp[c] = w;
        Vb[c] = v0;
    }
    __syncthreads();

    // Phase C: 5 Jacobi passes on [2,28)x[2,28)
    float* src = Vb;
    float* dst = Va;
    #pragma unroll 1
    for (int t = 0; t < 5; ++t) {
        for (int c = tid; c < 26 * 32; c += 256) {
            int li = 2 + (c >> 5), lj = c & 31;
            if (lj < 2 || lj >= 28) continue;
            float w = Wp[li * 32 + lj];
            float v;
            if (w < 0.0f) {
                v = -w - 1.0f;
            } else {
                int gi = gy0 + li, gj = gx0 + lj;
                int um = (gi > 0)      ? li - 1 : li;
                int dp = (gi < HH - 1) ? li + 1 : li;
                int lm = (gj > 0)      ? lj - 1 : lj;
                int rp = (gj < WW - 1) ? lj + 1 : lj;
                float s = src[um * 32 + lm] + src[um * 32 + lj] + src[um * 32 + rp]
                        + src[li * 32 + lm]                     + src[li * 32 + rp]
                        + src[dp * 32 + lm] + src[dp * 32 + lj] + src[dp * 32 + rp];
                v = s * 0.125f + w;
            }
            dst[li * 32 + lj] = v;
        }
        __syncthreads();
        float* tmp = src; src = dst; dst = tmp;
    }

    // output tile: one cell per thread
    {
        int li = 7 + (tid >> 4), lj = 7 + (tid & 15);
        Vfin[(gy0 + li) * WW + gx0 + lj] = src[li * 32 + lj];
    }
}

// ---------------- bilinear grid sample (align_corners, border clamp) ----------------
__global__ void sample_kernel(const float* __restrict__ x,
                              const float* __restrict__ V,
                              float* __restrict__ out) {
    int idx = blockIdx.x * 256 + threadIdx.x;
    float2 g2 = ((const float2*)x)[idx];
    float ix = (g2.x + 1.0f) * 0.5f * 511.0f;
    float iy = (g2.y + 1.0f) * 0.5f * 511.0f;
    ix = fminf(fmaxf(ix, 0.0f), 511.0f);
    iy = fminf(fmaxf(iy, 0.0f), 511.0f);
    int x0 = (int)floorf(ix), y0 = (int)floorf(iy);
    int x1 = min(x0 + 1, 511), y1 = min(y0 + 1, 511);
    float wx = ix - (float)x0, wy = iy - (float)y0;
    float v00 = V[y0 * 512 + x0], v01 = V[y0 * 512 + x1];
    float v10 = V[y1 * 512 + x0], v11 = V[y1 * 512 + x1];
    float v = v00 * (1.0f - wx) * (1.0f - wy) + v01 * wx * (1.0f - wy)
            + v10 * (1.0f - wx) * wy          + v11 * wx * wy;
    out[idx] = v;   // output 0
}

extern "C" void kernel_launch(void* const* d_in, const int* in_sizes, int n_in,
                              void* d_out, int out_size, void* d_ws, size_t ws_size,
                              hipStream_t stream) {
    const float* x    = (const float*)d_in[0];
    const int*   bt   = (const int*)d_in[1];
    const float* bc   = (const float*)d_in[2];
    const float* benc = (const float*)d_in[3];
    const float* Wh   = (const float*)d_in[4];
    const float* wout = (const float*)d_in[5];

    char* ws = (char*)d_ws;
    ushort_t* WT   = (ushort_t*)(ws + 4096);
    float*    C_ws = (float*)(ws + 262144);
    float*    Vfin = (float*)(ws + 262144 + 3 * (1 << 20));
    float*    outp = (float*)d_out;

    prep_kernel<<<32, 256, 0, stream>>>(Wh, WT);
    mlp_kernel<<<2048, 256, 0, stream>>>(x, WT, benc, wout, C_ws, outp);
    fused_solve_kernel<<<1024, 256, 0, stream>>>(bt, bc, C_ws, Vfin);
    sample_kernel<<<1024, 256, 0, stream>>>(x, Vfin, outp);
}

// Round 6
// 160.164 us; speedup vs baseline: 1.1898x; 1.1898x over previous
//
#include <hip/hip_runtime.h>
#include <hip/hip_bf16.h>

// LaplaceCostNet — MI355X (gfx950), round 6.
// R5 post-mortem: __launch_bounds__(256,4) -> 128-reg cap -> acc spilled to
// scratch (WRITE_SIZE 64 MB, FETCH 32 MB, MfmaUtil 11%). Weights-from-L2 never
// got a clean test. R6: same structure with
//  (1) __launch_bounds__(256,2) — no spills, clean weights-from-L2 test;
//  (2) encoding via HW sin/cos in REVOLUTIONS (drop the 2pi mul + libm range
//      reduction; fract + v_sin + v_cos), benc loads made wave-uniform (s_load);
//  (3) bf16 packing via v_cvt_pk_bf16_f32 (__float22bfloat162_rn).
//
// Workspace (bytes):
//   [4096   .. 135168)   WT bf16, linear: WT[l][n][k] = Wh[l][k][n]
//   [262144 .. +1MB)     C    fp32
//   [262144+3MB .. +4MB) Vfin fp32

typedef unsigned short ushort_t;
typedef short short8 __attribute__((ext_vector_type(8)));
typedef float floatx4 __attribute__((ext_vector_type(4)));

#define HH 512
#define WW 512
#define NPIX (HH*WW)

// act swizzle: element address in a 128-elem row, 16B-chunk XOR'd with row&15
#define SW(p, f) (((p) << 7) + (((((f) >> 3) ^ ((p) & 15))) << 3) + ((f) & 7))

__device__ inline unsigned int pk_bf16(float a, float b) {   // a -> low16, b -> high16
    __hip_bfloat162 h = __float22bfloat162_rn(float2{a, b});
    return *(unsigned int*)&h;
}
__device__ inline float bf2f(ushort_t u) {
    union { unsigned int i; float f; } v; v.i = ((unsigned int)u) << 16; return v.f;
}

// ---------------- prep: transpose+downcast weights (coalesced via LDS) ----------------
__global__ __launch_bounds__(256) void prep_kernel(const float* __restrict__ Wh,
                                                   ushort_t* __restrict__ WT) {
    __shared__ float trans[64 * 33];
    const int tid = threadIdx.x;
    const int l = blockIdx.x >> 3, ng = (blockIdx.x >> 2) & 1, kq = blockIdx.x & 3;
    const int n0 = ng * 64, k0 = kq * 32;
    const int ln = tid & 63, wv = tid >> 6;
    #pragma unroll
    for (int pass = 0; pass < 8; ++pass) {
        int k = k0 + pass * 4 + wv;
        trans[ln * 33 + (k - k0)] = Wh[l * 16384 + k * 128 + n0 + ln];
    }
    __syncthreads();
    {
        int n = tid >> 2, q = tid & 3;
        unsigned int w[4];
        #pragma unroll
        for (int j = 0; j < 4; ++j)
            w[j] = pk_bf16(trans[n * 33 + q * 8 + 2 * j], trans[n * 33 + q * 8 + 2 * j + 1]);
        *(uint4*)&WT[(l * 128 + n0 + n) * 128 + k0 + q * 8] = uint4{w[0], w[1], w[2], w[3]};
    }
}

// ---------------- MLP: enc + 4x (128x128 MFMA GEMM, relu) + output dot ----------------
// Weights = A operand straight from global/L2; activations = B operand in LDS.
__global__ __launch_bounds__(256, 2) void mlp_kernel(const float* __restrict__ x,
                                                     const ushort_t* __restrict__ WT,
                                                     const float* __restrict__ benc,
                                                     const float* __restrict__ wout,
                                                     float* __restrict__ C_ws,
                                                     float* __restrict__ outbuf) {
    __shared__ __align__(16) ushort_t act[128 * 128];   // 32 KB, swizzled rows
    const int tid = threadIdx.x;
    const int p0 = blockIdx.x * 128;
    const int lane = tid & 63, wave = tid >> 6;

    // --- Fourier encoding. h = tid>>7 is wave-uniform -> benc reads are scalar.
    // ref: enc = [cos(2pi*theta), sin(2pi*theta)]; HW v_sin/v_cos take REVOLUTIONS,
    // so compute theta (no 2pi), fract, then raw HW sin/cos.
    {
        int p = tid & 127, h = tid >> 7;    // thread covers f in [h*32, (h+1)*32)
        float2 xv = ((const float2*)x)[p0 + p];
        float xq0 = 0.5f + 0.5f * xv.x, xq1 = 0.5f + 0.5f * xv.y;
        const float4* b4 = (const float4*)benc;
        #pragma unroll 4
        for (int f2 = 0; f2 < 32; f2 += 2) {
            int f = h * 32 + f2;
            float4 b = b4[f >> 1];          // benc[2f .. 2f+3], wave-uniform
            float t0 = __builtin_amdgcn_fractf(xq0 * b.x + xq1 * b.y);
            float t1 = __builtin_amdgcn_fractf(xq0 * b.z + xq1 * b.w);
            float s0 = __builtin_amdgcn_sinf(t0), c0 = __builtin_amdgcn_cosf(t0);
            float s1 = __builtin_amdgcn_sinf(t1), c1 = __builtin_amdgcn_cosf(t1);
            *(unsigned int*)&act[SW(p, f)]      = pk_bf16(c0, c1);   // cos -> n = f
            *(unsigned int*)&act[SW(p, f + 64)] = pk_bf16(s0, s1);   // sin -> n = f+64
        }
    }

    const int quad = lane >> 4, l16 = lane & 15;
    const int ntb = (wave >> 1) * 64;   // out-neuron range
    const int ptb = (wave & 1) * 64;    // point range

    #pragma unroll 1
    for (int l = 0; l < 4; ++l) {
        __syncthreads();   // act ready (enc or previous writeback)

        floatx4 acc[4][4];
        #pragma unroll
        for (int i = 0; i < 4; ++i)
            #pragma unroll
            for (int j = 0; j < 4; ++j)
                acc[i][j] = floatx4{0.0f, 0.0f, 0.0f, 0.0f};

        #pragma unroll
        for (int ks = 0; ks < 4; ++ks) {
            int cs = ks * 4 + quad;           // this quad's 8-elem k-chunk
            short8 af[4], bv[4];
            #pragma unroll
            for (int i = 0; i < 4; ++i) {
                int r = ntb + i * 16 + l16;   // neuron row
                af[i] = *(const short8*)&WT[((l * 128 + r) << 7) + (cs << 3)];  // L2
            }
            #pragma unroll
            for (int j = 0; j < 4; ++j) {
                int p = ptb + j * 16 + l16;   // point row
                bv[j] = *(const short8*)&act[(p << 7) + ((cs ^ l16) << 3)];
            }
            #pragma unroll
            for (int i = 0; i < 4; ++i)
                #pragma unroll
                for (int j = 0; j < 4; ++j)
                    acc[i][j] = __builtin_amdgcn_mfma_f32_16x16x32_bf16(af[i], bv[j], acc[i][j], 0, 0, 0);
        }
        __syncthreads();   // all act reads done before overwrite

        // writeback relu(acc) (swizzled): lane -> point p, neurons n0..n0+3
        #pragma unroll
        for (int i = 0; i < 4; ++i) {
            #pragma unroll
            for (int j = 0; j < 4; ++j) {
                int p = ptb + j * 16 + l16;
                int n0 = ntb + i * 16 + quad * 4;
                uint2 pk;
                pk.x = pk_bf16(fmaxf(acc[i][j][0], 0.0f), fmaxf(acc[i][j][1], 0.0f));
                pk.y = pk_bf16(fmaxf(acc[i][j][2], 0.0f), fmaxf(acc[i][j][3], 0.0f));
                *(uint2*)&act[SW(p, n0)] = pk;
            }
        }
    }
    __syncthreads();

    // final linear: two threads per point, 64 MACs each + shuffle combine
    {
        int p = tid >> 1, h = tid & 1;
        const float4* wo4 = (const float4*)wout;
        float sum = 0.0f;
        #pragma unroll
        for (int g = 0; g < 8; ++g) {
            int ch = h * 8 + g;
            short8 v = *(const short8*)&act[(p << 7) + ((ch ^ (p & 15)) << 3)];
            float4 wa = wo4[ch * 2], wb = wo4[ch * 2 + 1];
            sum += bf2f((ushort_t)v[0]) * wa.x + bf2f((ushort_t)v[1]) * wa.y
                 + bf2f((ushort_t)v[2]) * wa.z + bf2f((ushort_t)v[3]) * wa.w
                 + bf2f((ushort_t)v[4]) * wb.x + bf2f((ushort_t)v[5]) * wb.y
                 + bf2f((ushort_t)v[6]) * wb.z + bf2f((ushort_t)v[7]) * wb.w;
        }
        float other = __shfl_xor(sum, 1);
        if (h == 0) {
            float tot = sum + other;
            C_ws[p0 + p] = tot;
            outbuf[NPIX + p0 + p] = tot;   // output 1: C
        }
    }
}

// ---------------- fused: cost (box5 + Cs + V0) + 5 Jacobi passes ----------------
// 16x16 output tiles (1024 blocks), halo 7 -> 30x30 region, LDS stride 32.
__global__ __launch_bounds__(256) void fused_solve_kernel(const int* __restrict__ bt,
                                                          const float* __restrict__ bc,
                                                          const float* __restrict__ C_ws,
                                                          float* __restrict__ Vfin) {
    __shared__ float Va[30 * 32];
    __shared__ float Vb[30 * 32];
    __shared__ float Wp[30 * 32];   // free -> Cs (>=0), pinned/out -> -(bc+1)
    const int tid = threadIdx.x;
    const int gx0 = (blockIdx.x & 31) * 16 - 7, gy0 = (blockIdx.x >> 5) * 16 - 7;

    for (int c = tid; c < 30 * 32; c += 256) {
        int li = c >> 5, lj = c & 31;
        int gi = gy0 + li, gj = gx0 + lj;
        float v = 0.0f;
        if (lj < 30 && gi >= 0 && gi < HH && gj >= 0 && gj < WW) {
            int g = gi * WW + gj;
            float b = bc[g];
            if (bt[g] == 1 && b > 0.0f) v = b;
        }
        Va[c] = v;
    }
    __syncthreads();

    for (int c = tid; c < 30 * 32; c += 256) {
        int li = c >> 5, lj = c & 31;
        int gi = gy0 + li, gj = gx0 + lj;
        float w = -1.0f, v0 = 0.0f;
        if (li >= 2 && li < 28 && lj >= 2 && lj < 28 &&
            gi >= 0 && gi < HH && gj >= 0 && gj < WW) {
            int g = gi * WW + gj;
            if (bt[g] == 0) {
                float s = 0.0f;
                #pragma unroll
                for (int di = 0; di < 5; ++di)
                    #pragma unroll
                    for (int dj = 0; dj < 5; ++dj)
                        s += Va[(li + di - 2) * 32 + lj + dj - 2];
                w = fmaxf(C_ws[g], 0.0f) + s * 0.04f;
                v0 = 100.0f;
            } else {
                float b = bc[g];
                w = -b - 1.0f;
                v0 = b;
            }
        }
        Wp[c] = w;
        Vb[c] = v0;
    }
    __syncthreads();

    float* src = Vb;
    float* dst = Va;
    #pragma unroll 1
    for (int t = 0; t < 5; ++t) {
        for (int c = tid; c < 26 * 32; c += 256) {
            int li = 2 + (c >> 5), lj = c & 31;
            if (lj < 2 || lj >= 28) continue;
            float w = Wp[li * 32 + lj];
            float v;
            if (w < 0.0f) {
                v = -w - 1.0f;
            } else {
                int gi = gy0 + li, gj = gx0 + lj;
                int um = (gi > 0)      ? li - 1 : li;
                int dp = (gi < HH - 1) ? li + 1 : li;
                int lm = (gj > 0)      ? lj - 1 : lj;
                int rp = (gj < WW - 1) ? lj + 1 : lj;
                float s = src[um * 32 + lm] + src[um * 32 + lj] + src[um * 32 + rp]
                        + src[li * 32 + lm]                     + src[li * 32 + rp]
                        + src[dp * 32 + lm] + src[dp * 32 + lj] + src[dp * 32 + rp];
                v = s * 0.125f + w;
            }
            dst[li * 32 + lj] = v;
        }
        __syncthreads();
        float* tmp = src; src = dst; dst = tmp;
    }

    {
        int li = 7 + (tid >> 4), lj = 7 + (tid & 15);
        Vfin[(gy0 + li) * WW + gx0 + lj] = src[li * 32 + lj];
    }
}

// ---------------- bilinear grid sample (align_corners, border clamp) ----------------
__global__ void sample_kernel(const float* __restrict__ x,
                              const float* __restrict__ V,
                              float* __restrict__ out) {
    int idx = blockIdx.x * 256 + threadIdx.x;
    float2 g2 = ((const float2*)x)[idx];
    float ix = (g2.x + 1.0f) * 0.5f * 511.0f;
    float iy = (g2.y + 1.0f) * 0.5f * 511.0f;
    ix = fminf(fmaxf(ix, 0.0f), 511.0f);
    iy = fminf(fmaxf(iy, 0.0f), 511.0f);
    int x0 = (int)floorf(ix), y0 = (int)floorf(iy);
    int x1 = min(x0 + 1, 511), y1 = min(y0 + 1, 511);
    float wx = ix - (float)x0, wy = iy - (float)y0;
    float v00 = V[y0 * 512 + x0], v01 = V[y0 * 512 + x1];
    float v10 = V[y1 * 512 + x0], v11 = V[y1 * 512 + x1];
    float v = v00 * (1.0f - wx) * (1.0f - wy) + v01 * wx * (1.0f - wy)
            + v10 * (1.0f - wx) * wy          + v11 * wx * wy;
    out[idx] = v;   // output 0
}

extern "C" void kernel_launch(void* const* d_in, const int* in_sizes, int n_in,
                              void* d_out, int out_size, void* d_ws, size_t ws_size,
                              hipStream_t stream) {
    const float* x    = (const float*)d_in[0];
    const int*   bt   = (const int*)d_in[1];
    const float* bc   = (const float*)d_in[2];
    const float* benc = (const float*)d_in[3];
    const float* Wh   = (const float*)d_in[4];
    const float* wout = (const float*)d_in[5];

    char* ws = (char*)d_ws;
    ushort_t* WT   = (ushort_t*)(ws + 4096);
    float*    C_ws = (float*)(ws + 262144);
    float*    Vfin = (float*)(ws + 262144 + 3 * (1 << 20));
    float*    outp = (float*)d_out;

    prep_kernel<<<32, 256, 0, stream>>>(Wh, WT);
    mlp_kernel<<<2048, 256, 0, stream>>>(x, WT, benc, wout, C_ws, outp);
    fused_solve_kernel<<<1024, 256, 0, stream>>>(bt, bc, C_ws, Vfin);
    sample_kernel<<<1024, 256, 0, stream>>>(x, Vfin, outp);
}

// Round 7
// 130.371 us; speedup vs baseline: 1.4617x; 1.2285x over previous
//
#include <hip/hip_runtime.h>
#include <hip/hip_bf16.h>

// LaplaceCostNet — MI355X (gfx950), round 7.
// R6 post-mortem: weights-from-L2 in the K-loop is latency-bound (MfmaUtil 15%,
// mlp 88.7 µs vs R4's 64.9 with LDS-staged weights). R7 = R4 mlp structure
// (pre-swizzled WT + global_load_lds dbuf staging) + R6 wins (HW sin/cos in
// revolutions, v_cvt_pk_bf16_f32 packing, wave-uniform benc reads).
//
// Workspace (bytes):
//   [4096   .. 135168)   WT bf16, PRE-SWIZZLED: row n stores logical chunk c at
//                        physical chunk pc = c ^ (n&15)   (16B chunks, 16/row)
//   [262144 .. +1MB)     C    fp32
//   [262144+3MB .. +4MB) Vfin fp32

typedef unsigned short ushort_t;
typedef short short8 __attribute__((ext_vector_type(8)));
typedef float floatx4 __attribute__((ext_vector_type(4)));

#define HH 512
#define WW 512
#define NPIX (HH*WW)

// act swizzle: element address in a 128-elem row, 16B-chunk XOR'd with row&15
#define SW(p, f) (((p) << 7) + (((((f) >> 3) ^ ((p) & 15))) << 3) + ((f) & 7))

__device__ inline unsigned int pk_bf16(float a, float b) {   // a->low16, b->high16
    __hip_bfloat162 h = __float22bfloat162_rn(float2{a, b});
    return *(unsigned int*)&h;
}
__device__ inline float bf2f(ushort_t u) {
    union { unsigned int i; float f; } v; v.i = ((unsigned int)u) << 16; return v.f;
}
__device__ inline void async_copy16(void* lds, const void* g) {
    __builtin_amdgcn_global_load_lds(
        (const __attribute__((address_space(1))) unsigned int*)g,
        (__attribute__((address_space(3))) unsigned int*)lds, 16, 0, 0);
}

// ---------------- prep: transpose+downcast+PRE-SWIZZLE weights (coalesced) ----------------
// 32 blocks: l = b>>3, ng = (b>>2)&1 (64-row n-half), kq = b&3 (32-col k-quarter).
__global__ __launch_bounds__(256) void prep_kernel(const float* __restrict__ Wh,
                                                   ushort_t* __restrict__ WT) {
    __shared__ float trans[64 * 33];
    const int tid = threadIdx.x;
    const int l = blockIdx.x >> 3, ng = (blockIdx.x >> 2) & 1, kq = blockIdx.x & 3;
    const int n0 = ng * 64, k0 = kq * 32;
    const int ln = tid & 63, wv = tid >> 6;
    #pragma unroll
    for (int pass = 0; pass < 8; ++pass) {
        int k = k0 + pass * 4 + wv;
        trans[ln * 33 + (k - k0)] = Wh[l * 16384 + k * 128 + n0 + ln];  // coalesced in n
    }
    __syncthreads();
    {
        int nl = tid >> 2, q = tid & 3;          // row-local n, quarter-local chunk
        int n = n0 + nl;
        int lc = kq * 4 + q;                      // logical chunk 0..15
        int pc = lc ^ (n & 15);                   // physical (swizzled) chunk
        unsigned int w[4];
        #pragma unroll
        for (int j = 0; j < 4; ++j)
            w[j] = pk_bf16(trans[nl * 33 + q * 8 + 2 * j], trans[nl * 33 + q * 8 + 2 * j + 1]);
        *(uint4*)&WT[(l * 128 + n) * 128 + pc * 8] = uint4{w[0], w[1], w[2], w[3]};
    }
}

// ---------------- MLP: enc + 4x (128x128 MFMA GEMM, relu) + output dot ----------------
__global__ __launch_bounds__(256, 2) void mlp_kernel(const float* __restrict__ x,
                                                     const ushort_t* __restrict__ WT,
                                                     const float* __restrict__ benc,
                                                     const float* __restrict__ wout,
                                                     float* __restrict__ C_ws,
                                                     float* __restrict__ outbuf) {
    __shared__ __align__(16) ushort_t act[128 * 128];   // 32 KB, swizzled rows
    __shared__ __align__(16) ushort_t wbuf[128 * 128];  // 32 KB, swizzled rows
    const int tid = threadIdx.x;
    const int p0 = blockIdx.x * 128;
    const int lane = tid & 63, wave = tid >> 6;

    // kick off async DMA of layer-0 weights (pre-swizzled -> linear copy)
    {
        const char* src = (const char*)WT;
        int base = wave * 512;
        #pragma unroll
        for (int c2 = 0; c2 < 8; ++c2) {
            int cb = base + c2 * 64;
            async_copy16(&wbuf[cb * 8], src + (cb + lane) * 16);
        }
    }

    // --- Fourier encoding: h = tid>>7 wave-uniform -> benc reads scalar.
    // ref enc = [cos(2pi*t), sin(2pi*t)]; HW v_sin/v_cos take REVOLUTIONS:
    // fract(t) then raw HW sin/cos (no 2pi, no libm range reduction).
    {
        int p = tid & 127, h = tid >> 7;    // this thread: f in [h*32, (h+1)*32)
        float2 xv = ((const float2*)x)[p0 + p];
        float xq0 = 0.5f + 0.5f * xv.x, xq1 = 0.5f + 0.5f * xv.y;
        const float4* b4 = (const float4*)benc;
        #pragma unroll 4
        for (int f2 = 0; f2 < 32; f2 += 2) {
            int f = h * 32 + f2;
            float4 b = b4[f >> 1];          // benc[2f .. 2f+3], wave-uniform
            float t0 = __builtin_amdgcn_fractf(xq0 * b.x + xq1 * b.y);
            float t1 = __builtin_amdgcn_fractf(xq0 * b.z + xq1 * b.w);
            float s0 = __builtin_amdgcn_sinf(t0), c0 = __builtin_amdgcn_cosf(t0);
            float s1 = __builtin_amdgcn_sinf(t1), c1 = __builtin_amdgcn_cosf(t1);
            *(unsigned int*)&act[SW(p, f)]      = pk_bf16(c0, c1);   // cos -> n = f
            *(unsigned int*)&act[SW(p, f + 64)] = pk_bf16(s0, s1);   // sin -> n = f+64
        }
    }

    const int quad = lane >> 4, l16 = lane & 15;
    const int ntb = (wave >> 1) * 64;   // out-neuron range
    const int ptb = (wave & 1) * 64;    // point range

    #pragma unroll 1
    for (int l = 0; l < 4; ++l) {
        __syncthreads();   // act ready + wbuf(l) DMA drained (barrier waits vmcnt)

        floatx4 acc[4][4];
        #pragma unroll
        for (int i = 0; i < 4; ++i)
            #pragma unroll
            for (int j = 0; j < 4; ++j)
                acc[i][j] = floatx4{0.0f, 0.0f, 0.0f, 0.0f};

        #pragma unroll
        for (int ks = 0; ks < 4; ++ks) {
            int cs = ks * 4 + quad;           // this quad's 8-elem k-chunk
            short8 af[4], bv[4];
            #pragma unroll
            for (int i = 0; i < 4; ++i) {
                int r = ntb + i * 16 + l16;   // neuron row; r&15 == l16
                af[i] = *(const short8*)&wbuf[(r << 7) + ((cs ^ l16) << 3)];
            }
            #pragma unroll
            for (int j = 0; j < 4; ++j) {
                int p = ptb + j * 16 + l16;   // point row
                bv[j] = *(const short8*)&act[(p << 7) + ((cs ^ l16) << 3)];
            }
            #pragma unroll
            for (int i = 0; i < 4; ++i)
                #pragma unroll
                for (int j = 0; j < 4; ++j)
                    acc[i][j] = __builtin_amdgcn_mfma_f32_16x16x32_bf16(af[i], bv[j], acc[i][j], 0, 0, 0);
        }
        __syncthreads();   // all wbuf/act reads done

        if (l < 3) {       // stage next layer during writeback
            const char* src = (const char*)WT + (l + 1) * 32768;
            int base = wave * 512;
            #pragma unroll
            for (int c2 = 0; c2 < 8; ++c2) {
                int cb = base + c2 * 64;
                async_copy16(&wbuf[cb * 8], src + (cb + lane) * 16);
            }
        }

        // writeback relu(acc) (swizzled): lane -> point p, neurons n0..n0+3
        #pragma unroll
        for (int i = 0; i < 4; ++i) {
            #pragma unroll
            for (int j = 0; j < 4; ++j) {
                int p = ptb + j * 16 + l16;
                int n0 = ntb + i * 16 + quad * 4;
                uint2 pk;
                pk.x = pk_bf16(fmaxf(acc[i][j][0], 0.0f), fmaxf(acc[i][j][1], 0.0f));
                pk.y = pk_bf16(fmaxf(acc[i][j][2], 0.0f), fmaxf(acc[i][j][3], 0.0f));
                *(uint2*)&act[SW(p, n0)] = pk;
            }
        }
    }
    __syncthreads();

    // final linear: two threads per point, 64 MACs each + shuffle combine
    {
        int p = tid >> 1, h = tid & 1;
        const float4* wo4 = (const float4*)wout;
        float sum = 0.0f;
        #pragma unroll
        for (int g = 0; g < 8; ++g) {
            int ch = h * 8 + g;
            short8 v = *(const short8*)&act[(p << 7) + ((ch ^ (p & 15)) << 3)];
            float4 wa = wo4[ch * 2], wb = wo4[ch * 2 + 1];
            sum += bf2f((ushort_t)v[0]) * wa.x + bf2f((ushort_t)v[1]) * wa.y
                 + bf2f((ushort_t)v[2]) * wa.z + bf2f((ushort_t)v[3]) * wa.w
                 + bf2f((ushort_t)v[4]) * wb.x + bf2f((ushort_t)v[5]) * wb.y
                 + bf2f((ushort_t)v[6]) * wb.z + bf2f((ushort_t)v[7]) * wb.w;
        }
        float other = __shfl_xor(sum, 1);
        if (h == 0) {
            float tot = sum + other;
            C_ws[p0 + p] = tot;
            outbuf[NPIX + p0 + p] = tot;   // output 1: C
        }
    }
}

// ---------------- fused: cost (box5 + Cs + V0) + 5 Jacobi passes ----------------
__global__ __launch_bounds__(256) void fused_solve_kernel(const int* __restrict__ bt,
                                                          const float* __restrict__ bc,
                                                          const float* __restrict__ C_ws,
                                                          float* __restrict__ Vfin) {
    __shared__ float Va[30 * 32];
    __shared__ float Vb[30 * 32];
    __shared__ float Wp[30 * 32];   // free -> Cs (>=0), pinned/out -> -(bc+1)
    const int tid = threadIdx.x;
    const int gx0 = (blockIdx.x & 31) * 16 - 7, gy0 = (blockIdx.x >> 5) * 16 - 7;

    for (int c = tid; c < 30 * 32; c += 256) {
        int li = c >> 5, lj = c & 31;
        int gi = gy0 + li, gj = gx0 + lj;
        float v = 0.0f;
        if (lj < 30 && gi >= 0 && gi < HH && gj >= 0 && gj < WW) {
            int g = gi * WW + gj;
            float b = bc[g];
            if (bt[g] == 1 && b > 0.0f) v = b;
        }
        Va[c] = v;
    }
    __syncthreads();

    for (int c = tid; c < 30 * 32; c += 256) {
        int li = c >> 5, lj = c & 31;
        int gi = gy0 + li, gj = gx0 + lj;
        float w = -1.0f, v0 = 0.0f;
        if (li >= 2 && li < 28 && lj >= 2 && lj < 28 &&
            gi >= 0 && gi < HH && gj >= 0 && gj < WW) {
            int g = gi * WW + gj;
            if (bt[g] == 0) {
                float s = 0.0f;
                #pragma unroll
                for (int di = 0; di < 5; ++di)
                    #pragma unroll
                    for (int dj = 0; dj < 5; ++dj)
                        s += Va[(li + di - 2) * 32 + lj + dj - 2];
                w = fmaxf(C_ws[g], 0.0f) + s * 0.04f;
                v0 = 100.0f;
            } else {
                float b = bc[g];
                w = -b - 1.0f;
                v0 = b;
            }
        }
        Wp[c] = w;
        Vb[c] = v0;
    }
    __syncthreads();

    float* src = Vb;
    float* dst = Va;
    #pragma unroll 1
    for (int t = 0; t < 5; ++t) {
        for (int c = tid; c < 26 * 32; c += 256) {
            int li = 2 + (c >> 5), lj = c & 31;
            if (lj < 2 || lj >= 28) continue;
            float w = Wp[li * 32 + lj];
            float v;
            if (w < 0.0f) {
                v = -w - 1.0f;
            } else {
                int gi = gy0 + li, gj = gx0 + lj;
                int um = (gi > 0)      ? li - 1 : li;
                int dp = (gi < HH - 1) ? li + 1 : li;
                int lm = (gj > 0)      ? lj - 1 : lj;
                int rp = (gj < WW - 1) ? lj + 1 : lj;
                float s = src[um * 32 + lm] + src[um * 32 + lj] + src[um * 32 + rp]
                        + src[li * 32 + lm]                     + src[li * 32 + rp]
                        + src[dp * 32 + lm] + src[dp * 32 + lj] + src[dp * 32 + rp];
                v = s * 0.125f + w;
            }
            dst[li * 32 + lj] = v;
        }
        __syncthreads();
        float* tmp = src; src = dst; dst = tmp;
    }

    {
        int li = 7 + (tid >> 4), lj = 7 + (tid & 15);
        Vfin[(gy0 + li) * WW + gx0 + lj] = src[li * 32 + lj];
    }
}

// ---------------- bilinear grid sample (align_corners, border clamp) ----------------
__global__ void sample_kernel(const float* __restrict__ x,
                              const float* __restrict__ V,
                              float* __restrict__ out) {
    int idx = blockIdx.x * 256 + threadIdx.x;
    float2 g2 = ((const float2*)x)[idx];
    float ix = (g2.x + 1.0f) * 0.5f * 511.0f;
    float iy = (g2.y + 1.0f) * 0.5f * 511.0f;
    ix = fminf(fmaxf(ix, 0.0f), 511.0f);
    iy = fminf(fmaxf(iy, 0.0f), 511.0f);
    int x0 = (int)floorf(ix), y0 = (int)floorf(iy);
    int x1 = min(x0 + 1, 511), y1 = min(y0 + 1, 511);
    float wx = ix - (float)x0, wy = iy - (float)y0;
    float v00 = V[y0 * 512 + x0], v01 = V[y0 * 512 + x1];
    float v10 = V[y1 * 512 + x0], v11 = V[y1 * 512 + x1];
    float v = v00 * (1.0f - wx) * (1.0f - wy) + v01 * wx * (1.0f - wy)
            + v10 * (1.0f - wx) * wy          + v11 * wx * wy;
    out[idx] = v;   // output 0
}

extern "C" void kernel_launch(void* const* d_in, const int* in_sizes, int n_in,
                              void* d_out, int out_size, void* d_ws, size_t ws_size,
                              hipStream_t stream) {
    const float* x    = (const float*)d_in[0];
    const int*   bt   = (const int*)d_in[1];
    const float* bc   = (const float*)d_in[2];
    const float* benc = (const float*)d_in[3];
    const float* Wh   = (const float*)d_in[4];
    const float* wout = (const float*)d_in[5];

    char* ws = (char*)d_ws;
    ushort_t* WT   = (ushort_t*)(ws + 4096);
    float*    C_ws = (float*)(ws + 262144);
    float*    Vfin = (float*)(ws + 262144 + 3 * (1 << 20));
    float*    outp = (float*)d_out;

    prep_kernel<<<32, 256, 0, stream>>>(Wh, WT);
    mlp_kernel<<<2048, 256, 0, stream>>>(x, WT, benc, wout, C_ws, outp);
    fused_solve_kernel<<<1024, 256, 0, stream>>>(bt, bc, C_ws, Vfin);
    sample_kernel<<<1024, 256, 0, stream>>>(x, Vfin, outp);
}

// Round 8
// 128.525 us; speedup vs baseline: 1.4827x; 1.0144x over previous
//
#include <hip/hip_runtime.h>
#include <hip/hip_bf16.h>

// LaplaceCostNet — MI355X (gfx950), round 8.
// R7: mlp 57 µs at 2 blocks/CU (LDS 64 KB) — barrier-bound (MFMA-busy ~13 µs
// vs 14.3 µs floor; both pipes half-idle). R8:
//  (1) 64-point blocks: LDS 48.5 KB -> 3 blocks/CU, barriers hide 3-deep;
//  (2) final dot computed from layer-3 accumulators (shfl quad-reduce + 512B
//      pbuf) — deletes layer-3 writeback AND the 8x ds_read_b128 epilogue;
//  (3) carried: pre-swizzled WT + global_load_lds(16B), HW sin/cos (revolutions).
//
// Workspace (bytes):
//   [4096   .. 135168)   WT bf16, PRE-SWIZZLED: row n stores logical chunk c at
//                        physical chunk pc = c ^ (n&15)   (16B chunks, 16/row)
//   [262144 .. +1MB)     C    fp32
//   [262144+3MB .. +4MB) Vfin fp32

typedef unsigned short ushort_t;
typedef short short8 __attribute__((ext_vector_type(8)));
typedef float floatx4 __attribute__((ext_vector_type(4)));

#define HH 512
#define WW 512
#define NPIX (HH*WW)

// act swizzle: element address in a 128-elem row, 16B-chunk XOR'd with row&15
#define SW(p, f) (((p) << 7) + (((((f) >> 3) ^ ((p) & 15))) << 3) + ((f) & 7))

__device__ inline unsigned int pk_bf16(float a, float b) {   // a->low16, b->high16
    __hip_bfloat162 h = __float22bfloat162_rn(float2{a, b});
    return *(unsigned int*)&h;
}
__device__ inline float bf2f(ushort_t u) {
    union { unsigned int i; float f; } v; v.i = ((unsigned int)u) << 16; return v.f;
}
__device__ inline void async_copy16(void* lds, const void* g) {
    __builtin_amdgcn_global_load_lds(
        (const __attribute__((address_space(1))) unsigned int*)g,
        (__attribute__((address_space(3))) unsigned int*)lds, 16, 0, 0);
}

// ---------------- prep: transpose+downcast+PRE-SWIZZLE weights (coalesced) ----------------
__global__ __launch_bounds__(256) void prep_kernel(const float* __restrict__ Wh,
                                                   ushort_t* __restrict__ WT) {
    __shared__ float trans[64 * 33];
    const int tid = threadIdx.x;
    const int l = blockIdx.x >> 3, ng = (blockIdx.x >> 2) & 1, kq = blockIdx.x & 3;
    const int n0 = ng * 64, k0 = kq * 32;
    const int ln = tid & 63, wv = tid >> 6;
    #pragma unroll
    for (int pass = 0; pass < 8; ++pass) {
        int k = k0 + pass * 4 + wv;
        trans[ln * 33 + (k - k0)] = Wh[l * 16384 + k * 128 + n0 + ln];  // coalesced in n
    }
    __syncthreads();
    {
        int nl = tid >> 2, q = tid & 3;
        int n = n0 + nl;
        int lc = kq * 4 + q;                      // logical chunk 0..15
        int pc = lc ^ (n & 15);                   // physical (swizzled) chunk
        unsigned int w[4];
        #pragma unroll
        for (int j = 0; j < 4; ++j)
            w[j] = pk_bf16(trans[nl * 33 + q * 8 + 2 * j], trans[nl * 33 + q * 8 + 2 * j + 1]);
        *(uint4*)&WT[(l * 128 + n) * 128 + pc * 8] = uint4{w[0], w[1], w[2], w[3]};
    }
}

// ---------------- MLP: 64 points/block, 4096 blocks, 3 blocks/CU ----------------
__global__ __launch_bounds__(256, 3) void mlp_kernel(const float* __restrict__ x,
                                                     const ushort_t* __restrict__ WT,
                                                     const float* __restrict__ benc,
                                                     const float* __restrict__ wout,
                                                     float* __restrict__ C_ws,
                                                     float* __restrict__ outbuf) {
    __shared__ __align__(16) ushort_t act[64 * 128];    // 16 KB, swizzled rows (points)
    __shared__ __align__(16) ushort_t wbuf[128 * 128];  // 32 KB, swizzled rows (neurons)
    __shared__ float pbuf[4 * 32];                      // 512 B, cross-wave dot partials
    const int tid = threadIdx.x;
    const int p0 = blockIdx.x * 64;
    const int lane = tid & 63, wave = tid >> 6;

    // async DMA of layer-0 weights (pre-swizzled -> linear copy)
    {
        const char* src = (const char*)WT;
        int base = wave * 512;
        #pragma unroll
        for (int c2 = 0; c2 < 8; ++c2) {
            int cb = base + c2 * 64;
            async_copy16(&wbuf[cb * 8], src + (cb + lane) * 16);
        }
    }

    // --- Fourier encoding: p = tid&63, h = wave (uniform -> scalar benc reads).
    // ref enc = [cos(2pi t), sin(2pi t)]; HW v_sin/v_cos take REVOLUTIONS:
    // fract(t) then raw HW sin/cos.
    {
        int p = tid & 63, h = tid >> 6;     // 16 freqs per thread
        float2 xv = ((const float2*)x)[p0 + p];
        float xq0 = 0.5f + 0.5f * xv.x, xq1 = 0.5f + 0.5f * xv.y;
        const float4* b4 = (const float4*)benc;
        #pragma unroll 4
        for (int f2 = 0; f2 < 16; f2 += 2) {
            int f = h * 16 + f2;
            float4 b = b4[f >> 1];          // benc[2f..2f+3], wave-uniform
            float t0 = __builtin_amdgcn_fractf(xq0 * b.x + xq1 * b.y);
            float t1 = __builtin_amdgcn_fractf(xq0 * b.z + xq1 * b.w);
            float s0 = __builtin_amdgcn_sinf(t0), c0 = __builtin_amdgcn_cosf(t0);
            float s1 = __builtin_amdgcn_sinf(t1), c1 = __builtin_amdgcn_cosf(t1);
            *(unsigned int*)&act[SW(p, f)]      = pk_bf16(c0, c1);   // cos -> n=f
            *(unsigned int*)&act[SW(p, f + 64)] = pk_bf16(s0, s1);   // sin -> n=f+64
        }
    }

    const int quad = lane >> 4, l16 = lane & 15;
    const int ntb = (wave >> 1) * 64;   // out-neuron range (64 wide)
    const int ptb = (wave & 1) * 32;    // point range (32 wide)

    floatx4 acc[4][2];
    #pragma unroll 1
    for (int l = 0; l < 4; ++l) {
        __syncthreads();   // act ready + wbuf(l) DMA drained

        #pragma unroll
        for (int i = 0; i < 4; ++i)
            #pragma unroll
            for (int j = 0; j < 2; ++j)
                acc[i][j] = floatx4{0.0f, 0.0f, 0.0f, 0.0f};

        #pragma unroll
        for (int ks = 0; ks < 4; ++ks) {
            int cs = ks * 4 + quad;           // this quad's 8-elem k-chunk
            short8 af[4], bv[2];
            #pragma unroll
            for (int i = 0; i < 4; ++i) {
                int r = ntb + i * 16 + l16;   // neuron row
                af[i] = *(const short8*)&wbuf[(r << 7) + ((cs ^ l16) << 3)];
            }
            #pragma unroll
            for (int j = 0; j < 2; ++j) {
                int p = ptb + j * 16 + l16;   // point row
                bv[j] = *(const short8*)&act[(p << 7) + ((cs ^ l16) << 3)];
            }
            #pragma unroll
            for (int i = 0; i < 4; ++i)
                #pragma unroll
                for (int j = 0; j < 2; ++j)
                    acc[i][j] = __builtin_amdgcn_mfma_f32_16x16x32_bf16(af[i], bv[j], acc[i][j], 0, 0, 0);
        }

        if (l == 3) break;     // layer-3 results consumed from registers below
        __syncthreads();       // all wbuf/act reads done

        // stage next layer during writeback
        {
            const char* src = (const char*)WT + (l + 1) * 32768;
            int base = wave * 512;
            #pragma unroll
            for (int c2 = 0; c2 < 8; ++c2) {
                int cb = base + c2 * 64;
                async_copy16(&wbuf[cb * 8], src + (cb + lane) * 16);
            }
        }

        // writeback relu(acc) (swizzled): lane -> point p, neurons n0..n0+3
        #pragma unroll
        for (int i = 0; i < 4; ++i) {
            #pragma unroll
            for (int j = 0; j < 2; ++j) {
                int p = ptb + j * 16 + l16;
                int n0 = ntb + i * 16 + quad * 4;
                uint2 pk;
                pk.x = pk_bf16(fmaxf(acc[i][j][0], 0.0f), fmaxf(acc[i][j][1], 0.0f));
                pk.y = pk_bf16(fmaxf(acc[i][j][2], 0.0f), fmaxf(acc[i][j][3], 0.0f));
                *(uint2*)&act[SW(p, n0)] = pk;
            }
        }
    }

    // final linear from registers: lane sums its 16 neurons, shfl-reduce quads,
    // then cross-wave (ntb 0 vs 64) combine through pbuf.
    {
        float4 wv[4];
        #pragma unroll
        for (int i = 0; i < 4; ++i)
            wv[i] = *(const float4*)&wout[ntb + i * 16 + quad * 4];
        #pragma unroll
        for (int j = 0; j < 2; ++j) {
            float s = 0.0f;
            #pragma unroll
            for (int i = 0; i < 4; ++i) {
                s += fmaxf(acc[i][j][0], 0.0f) * wv[i].x
                   + fmaxf(acc[i][j][1], 0.0f) * wv[i].y
                   + fmaxf(acc[i][j][2], 0.0f) * wv[i].z
                   + fmaxf(acc[i][j][3], 0.0f) * wv[i].w;
            }
            s += __shfl_xor(s, 16);
            s += __shfl_xor(s, 32);           // now: sum over this wave's 64 neurons
            if (quad == j) pbuf[wave * 32 + j * 16 + l16] = s;
        }
    }
    __syncthreads();
    if (tid < 64) {
        int p = tid;
        int half = p >> 5, idx = p & 31;      // waves {half, half+2} own this point
        float tot = pbuf[half * 32 + idx] + pbuf[(half + 2) * 32 + idx];
        C_ws[p0 + p] = tot;
        outbuf[NPIX + p0 + p] = tot;          // output 1: C
    }
}

// ---------------- fused: cost (box5 + Cs + V0) + 5 Jacobi passes ----------------
__global__ __launch_bounds__(256) void fused_solve_kernel(const int* __restrict__ bt,
                                                          const float* __restrict__ bc,
                                                          const float* __restrict__ C_ws,
                                                          float* __restrict__ Vfin) {
    __shared__ float Va[30 * 32];
    __shared__ float Vb[30 * 32];
    __shared__ float Wp[30 * 32];   // free -> Cs (>=0), pinned/out -> -(bc+1)
    const int tid = threadIdx.x;
    const int gx0 = (blockIdx.x & 31) * 16 - 7, gy0 = (blockIdx.x >> 5) * 16 - 7;

    for (int c = tid; c < 30 * 32; c += 256) {
        int li = c >> 5, lj = c & 31;
        int gi = gy0 + li, gj = gx0 + lj;
        float v = 0.0f;
        if (lj < 30 && gi >= 0 && gi < HH && gj >= 0 && gj < WW) {
            int g = gi * WW + gj;
            float b = bc[g];
            if (bt[g] == 1 && b > 0.0f) v = b;
        }
        Va[c] = v;
    }
    __syncthreads();

    for (int c = tid; c < 30 * 32; c += 256) {
        int li = c >> 5, lj = c & 31;
        int gi = gy0 + li, gj = gx0 + lj;
        float w = -1.0f, v0 = 0.0f;
        if (li >= 2 && li < 28 && lj >= 2 && lj < 28 &&
            gi >= 0 && gi < HH && gj >= 0 && gj < WW) {
            int g = gi * WW + gj;
            if (bt[g] == 0) {
                float s = 0.0f;
                #pragma unroll
                for (int di = 0; di < 5; ++di)
                    #pragma unroll
                    for (int dj = 0; dj < 5; ++dj)
                        s += Va[(li + di - 2) * 32 + lj + dj - 2];
                w = fmaxf(C_ws[g], 0.0f) + s * 0.04f;
                v0 = 100.0f;
            } else {
                float b = bc[g];
                w = -b - 1.0f;
                v0 = b;
            }
        }
        Wp[c] = w;
        Vb[c] = v0;
    }
    __syncthreads();

    float* src = Vb;
    float* dst = Va;
    #pragma unroll 1
    for (int t = 0; t < 5; ++t) {
        for (int c = tid; c < 26 * 32; c += 256) {
            int li = 2 + (c >> 5), lj = c & 31;
            if (lj < 2 || lj >= 28) continue;
            float w = Wp[li * 32 + lj];
            float v;
            if (w < 0.0f) {
                v = -w - 1.0f;
            } else {
                int gi = gy0 + li, gj = gx0 + lj;
                int um = (gi > 0)      ? li - 1 : li;
                int dp = (gi < HH - 1) ? li + 1 : li;
                int lm = (gj > 0)      ? lj - 1 : lj;
                int rp = (gj < WW - 1) ? lj + 1 : lj;
                float s = src[um * 32 + lm] + src[um * 32 + lj] + src[um * 32 + rp]
                        + src[li * 32 + lm]                     + src[li * 32 + rp]
                        + src[dp * 32 + lm] + src[dp * 32 + lj] + src[dp * 32 + rp];
                v = s * 0.125f + w;
            }
            dst[li * 32 + lj] = v;
        }
        __syncthreads();
        float* tmp = src; src = dst; dst = tmp;
    }

    {
        int li = 7 + (tid >> 4), lj = 7 + (tid & 15);
        Vfin[(gy0 + li) * WW + gx0 + lj] = src[li * 32 + lj];
    }
}

// ---------------- bilinear grid sample (align_corners, border clamp) ----------------
__global__ void sample_kernel(const float* __restrict__ x,
                              const float* __restrict__ V,
                              float* __restrict__ out) {
    int idx = blockIdx.x * 256 + threadIdx.x;
    float2 g2 = ((const float2*)x)[idx];
    float ix = (g2.x + 1.0f) * 0.5f * 511.0f;
    float iy = (g2.y + 1.0f) * 0.5f * 511.0f;
    ix = fminf(fmaxf(ix, 0.0f), 511.0f);
    iy = fminf(fmaxf(iy, 0.0f), 511.0f);
    int x0 = (int)floorf(ix), y0 = (int)floorf(iy);
    int x1 = min(x0 + 1, 511), y1 = min(y0 + 1, 511);
    float wx = ix - (float)x0, wy = iy - (float)y0;
    float v00 = V[y0 * 512 + x0], v01 = V[y0 * 512 + x1];
    float v10 = V[y1 * 512 + x0], v11 = V[y1 * 512 + x1];
    float v = v00 * (1.0f - wx) * (1.0f - wy) + v01 * wx * (1.0f - wy)
            + v10 * (1.0f - wx) * wy          + v11 * wx * wy;
    out[idx] = v;   // output 0
}

extern "C" void kernel_launch(void* const* d_in, const int* in_sizes, int n_in,
                              void* d_out, int out_size, void* d_ws, size_t ws_size,
                              hipStream_t stream) {
    const float* x    = (const float*)d_in[0];
    const int*   bt   = (const int*)d_in[1];
    const float* bc   = (const float*)d_in[2];
    const float* benc = (const float*)d_in[3];
    const float* Wh   = (const float*)d_in[4];
    const float* wout = (const float*)d_in[5];

    char* ws = (char*)d_ws;
    ushort_t* WT   = (ushort_t*)(ws + 4096);
    float*    C_ws = (float*)(ws + 262144);
    float*    Vfin = (float*)(ws + 262144 + 3 * (1 << 20));
    float*    outp = (float*)d_out;

    prep_kernel<<<32, 256, 0, stream>>>(Wh, WT);
    mlp_kernel<<<4096, 256, 0, stream>>>(x, WT, benc, wout, C_ws, outp);
    fused_solve_kernel<<<1024, 256, 0, stream>>>(bt, bc, C_ws, Vfin);
    sample_kernel<<<1024, 256, 0, stream>>>(x, Vfin, outp);
}